// Round 2
// baseline (45.951 us; speedup 1.0000x reference)
//
#include <hip/hip_runtime.h>

// Fixed problem shapes
#define N_PTS 2048
#define D_DIM 64
#define N_J   20
#define KD    192    // 64 (P) + 120 (W lifted features) + 8 zero pad
#define LDSW  232    // padded LDS row stride (bf16 elems); 464 B -> uniform bank phases
#define T_TILES 32   // 2048/64
#define NTILES 528   // T*(T+1)/2 upper-triangle 64x64 tiles
#define NUM_PAIRS_INV (1.0f / 2098175.0f)   // 1 / (N*(N+1)/2 - 1)

typedef __attribute__((ext_vector_type(8))) short bf16x8;   // MFMA A/B frag (8 bf16)
typedef __attribute__((ext_vector_type(4))) float f32x4;    // MFMA C/D frag

// round-to-nearest-even f32 -> bf16 bits
__device__ inline unsigned short f2bf(float f) {
    union { float f; unsigned int u; } v; v.f = f;
    unsigned int u = v.u;
    return (unsigned short)((u + 0x7FFFu + ((u >> 16) & 1u)) >> 16);
}

// ---------------------------------------------------------------------------
// Kernel 1: build bf16 feature matrix Gb[N][192] and exact f32 sq_norms[N].
//   Gb[i][0:64]   = bf16(predictions[i])
//   Gb[i][64:184] = bf16 of per-joint lifted features of unit u:
//                   (x^2, y^2, z^2, s2*xy, s2*xz, s2*yz), s2=sqrt(2)
//   Gb[i][184:192]= 0
// => dot(G_i,G_j) over [0,64)  = p_i.p_j ;  over [64,192) = sum_k cos_k^2
// ---------------------------------------------------------------------------
__global__ __launch_bounds__(64)
void precompute_kernel(const float* __restrict__ pred,
                       const float* __restrict__ data,
                       unsigned short* __restrict__ Gb,
                       float* __restrict__ sq) {
    const int i = blockIdx.x;
    const int t = threadIdx.x;

    float p = pred[i * D_DIM + t];
    Gb[i * KD + t] = f2bf(p);
    float v = p * p;
    #pragma unroll
    for (int off = 32; off > 0; off >>= 1) v += __shfl_down(v, off);
    if (t == 0) sq[i] = v;

    if (t < N_J) {
        const float x0 = data[(i * N_J + t) * 3 + 0];
        const float y0 = data[(i * N_J + t) * 3 + 1];
        const float z0 = data[(i * N_J + t) * 3 + 2];
        const float n2 = x0 * x0 + y0 * y0 + z0 * z0;
        const float inv = rsqrtf(fmaxf(n2, 1e-30f));
        const float x = x0 * inv, y = y0 * inv, z = z0 * inv;
        const float s2 = 1.4142135623730951f;
        unsigned short* g = &Gb[i * KD + D_DIM + t * 6];
        g[0] = f2bf(x * x);
        g[1] = f2bf(y * y);
        g[2] = f2bf(z * z);
        g[3] = f2bf(s2 * x * y);
        g[4] = f2bf(s2 * x * z);
        g[5] = f2bf(s2 * y * z);
    }
    if (t < 8) Gb[i * KD + D_DIM + N_J * 6 + t] = 0;
}

// ---------------------------------------------------------------------------
// Kernel 2: one block per 64x64 upper-triangle pair tile. 4 waves; wave w owns
// a 16-row strip x 64 cols = 4 MFMA tiles of 16x16. K=192 in 6 steps of 32:
// steps 0-1 -> accP (p-dot), steps 2-5 -> accW (cos^2-dot). Epilogue computes
// |dist - dis| per pair, wave-reduces, one atomicAdd per wave.
// ---------------------------------------------------------------------------
__global__ __launch_bounds__(256)
void pairloss_kernel(const unsigned short* __restrict__ Gb,
                     const float* __restrict__ sq,
                     float* __restrict__ out) {
    __shared__ unsigned short Ash[64 * LDSW];
    __shared__ unsigned short Bsh[64 * LDSW];

    // triangular tile decode
    int t = blockIdx.x;
    int ib = 0;
    while (t >= T_TILES - ib) { t -= (T_TILES - ib); ++ib; }
    const int jb = ib + t;

    const int tid = threadIdx.x;

    // stage A (rows of ib) and B (rows of jb): 64 rows x 24 chunks of 16B each
    #pragma unroll
    for (int q = 0; q < 6; ++q) {
        const int c   = q * 256 + tid;
        const int row = c / 24;
        const int kch = c % 24;
        const uint4 a = *(const uint4*)&Gb[(ib * 64 + row) * KD + kch * 8];
        *(uint4*)&Ash[row * LDSW + kch * 8] = a;
        const uint4 b = *(const uint4*)&Gb[(jb * 64 + row) * KD + kch * 8];
        *(uint4*)&Bsh[row * LDSW + kch * 8] = b;
    }
    __syncthreads();

    const int w  = tid >> 6;   // wave id 0..3 -> row strip
    const int l  = tid & 63;
    const int lr = l & 15;     // frag row/col index
    const int kg = l >> 4;     // k-group (8 consecutive k per group)

    f32x4 accP[4], accW[4];
    #pragma unroll
    for (int c4 = 0; c4 < 4; ++c4) {
        accP[c4] = (f32x4){0.f, 0.f, 0.f, 0.f};
        accW[c4] = (f32x4){0.f, 0.f, 0.f, 0.f};
    }

    const unsigned short* Abase = &Ash[(w * 16 + lr) * LDSW + kg * 8];
    const unsigned short* Bbase = &Bsh[lr * LDSW + kg * 8];

    #pragma unroll
    for (int ks = 0; ks < 6; ++ks) {
        const bf16x8 af = *(const bf16x8*)(Abase + ks * 32);
        #pragma unroll
        for (int c4 = 0; c4 < 4; ++c4) {
            const bf16x8 bf = *(const bf16x8*)(Bbase + c4 * 16 * LDSW + ks * 32);
            if (ks < 2)
                accP[c4] = __builtin_amdgcn_mfma_f32_16x16x32_bf16(af, bf, accP[c4], 0, 0, 0);
            else
                accW[c4] = __builtin_amdgcn_mfma_f32_16x16x32_bf16(af, bf, accW[c4], 0, 0, 0);
        }
    }

    // epilogue: D[row=(l>>4)*4+reg][col=l&15] per 16x16 tile
    const int i0 = ib * 64 + w * 16 + kg * 4;
    float sqi[4];
    #pragma unroll
    for (int r = 0; r < 4; ++r) sqi[r] = sq[i0 + r];

    float local = 0.0f;
    #pragma unroll
    for (int c4 = 0; c4 < 4; ++c4) {
        const int j   = jb * 64 + c4 * 16 + lr;
        const float sqj = sq[j];
        #pragma unroll
        for (int r = 0; r < 4; ++r) {
            const int i = i0 + r;
            if (j > i) {
                const float d2   = fmaxf(sqi[r] + sqj - 2.0f * accP[c4][r], 0.0f);
                const float dist = sqrtf(d2);
                const float s    = fmaxf((float)N_J - accW[c4][r], 0.0f);
                local += fabsf(dist - sqrtf(s));
            }
        }
    }

    // wave reduction + one atomic per wave (device scope)
    #pragma unroll
    for (int off = 32; off > 0; off >>= 1) local += __shfl_down(local, off);
    if (l == 0) atomicAdd(out, local * NUM_PAIRS_INV);
}

// ---------------------------------------------------------------------------
extern "C" void kernel_launch(void* const* d_in, const int* in_sizes, int n_in,
                              void* d_out, int out_size, void* d_ws, size_t ws_size,
                              hipStream_t stream) {
    const float* pred = (const float*)d_in[0];   // [2048, 64] f32
    const float* data = (const float*)d_in[1];   // [2048, 20, 3] f32
    float* out = (float*)d_out;

    unsigned short* Gb = (unsigned short*)d_ws;                       // 786432 B
    float* sq = (float*)((char*)d_ws + (size_t)N_PTS * KD * 2);       // 8192 B

    hipMemsetAsync(d_out, 0, sizeof(float), stream);
    precompute_kernel<<<N_PTS, 64, 0, stream>>>(pred, data, Gb, sq);
    pairloss_kernel<<<NTILES, 256, 0, stream>>>(Gb, sq, out);
}

// Round 3
// 19.787 us; speedup vs baseline: 2.3223x; 2.3223x over previous
//
#include <hip/hip_runtime.h>

// Fixed problem shapes
#define N_PTS 2048
#define D_DIM 64
#define N_J   20
#define LDSW  232    // padded LDS row stride in bf16 elems (464 B = 29 x 16B slots
                     // -> row-to-row 16B-slot phase advances 29 mod 8 = 5: conflict-free b128)
#define T_TILES 32   // 2048/64
#define NTILES 528   // T*(T+1)/2 upper-triangle 64x64 tiles
#define NUM_PAIRS_D 2098175.0   // N*(N+1)/2 - 1 (reference normalizer)

typedef __attribute__((ext_vector_type(8))) short bf16x8;   // MFMA A/B frag
typedef __attribute__((ext_vector_type(4))) float f32x4;    // MFMA C/D frag

// round-to-nearest-even f32 -> bf16 bits
__device__ inline unsigned short f2bf(float f) {
    union { float f; unsigned int u; } v; v.f = f;
    unsigned int u = v.u;
    return (unsigned short)((u + 0x7FFFu + ((u >> 16) & 1u)) >> 16);
}
__device__ inline unsigned int pack2(float lo, float hi) {
    return (unsigned int)f2bf(lo) | ((unsigned int)f2bf(hi) << 16);
}

// ---------------------------------------------------------------------------
// One block per 64x64 upper-triangle pair tile. Stages bf16 feature rows
// directly from pred/data into LDS (cols 0:64 = pred, 64:184 = per-joint
// lifted cos^2 features, 184:192 = 0 pad), then 4 waves x 4 MFMA col-tiles,
// K=192 in 6 steps of 32 (2 -> accP, 4 -> accW). Epilogue: |dist-dis| per
// strict-upper pair, wave reduce, ONE plain store per block (no atomics).
// ---------------------------------------------------------------------------
__global__ __launch_bounds__(256)
void pairloss_kernel(const float* __restrict__ pred,
                     const float* __restrict__ data,
                     float* __restrict__ partials) {
    __shared__ unsigned short Ash[64 * LDSW];
    __shared__ unsigned short Bsh[64 * LDSW];
    __shared__ float sqA[64], sqB[64], wsum[4];

    // triangular tile decode
    int t = blockIdx.x;
    int ib = 0;
    while (t >= T_TILES - ib) { t -= (T_TILES - ib); ++ib; }
    const int jb = ib + t;

    const int tid = threadIdx.x;

    // ---- staging: threads 0..127 build A (rows of ib), 128..255 build B ----
    {
        const int half = tid >> 7;          // 0 = A, 1 = B
        const int r    = (tid >> 1) & 63;   // row within tile
        const int h    = tid & 1;           // half-row worker (pair lanes l, l^1)
        const int grow = (half ? jb : ib) * 64 + r;
        unsigned short* __restrict__ sh = half ? Bsh : Ash;

        // pred part: this worker's 32 floats -> 32 bf16 (4 x uint4 LDS stores)
        const float4* __restrict__ p4 = (const float4*)&pred[grow * D_DIM + h * 32];
        float s = 0.f;
        #pragma unroll
        for (int q = 0; q < 4; ++q) {
            const float4 v0 = p4[2 * q];
            const float4 v1 = p4[2 * q + 1];
            s += v0.x * v0.x + v0.y * v0.y + v0.z * v0.z + v0.w * v0.w;
            s += v1.x * v1.x + v1.y * v1.y + v1.z * v1.z + v1.w * v1.w;
            uint4 u;
            u.x = pack2(v0.x, v0.y);
            u.y = pack2(v0.z, v0.w);
            u.z = pack2(v1.x, v1.y);
            u.w = pack2(v1.z, v1.w);
            *(uint4*)&sh[r * LDSW + h * 32 + q * 8] = u;
        }
        s += __shfl_xor(s, 1);              // combine the two half-row sums
        if (h == 0) (half ? sqB : sqA)[r] = s;

        // joint part: this worker's 10 joints (30 contiguous floats)
        const float2* __restrict__ d2 = (const float2*)&data[grow * (N_J * 3) + h * 30];
        float buf[30];
        #pragma unroll
        for (int q = 0; q < 15; ++q) {
            const float2 v = d2[q];
            buf[2 * q] = v.x; buf[2 * q + 1] = v.y;
        }
        const float s2 = 1.4142135623730951f;
        #pragma unroll
        for (int jj = 0; jj < 10; ++jj) {
            float x = buf[3 * jj], y = buf[3 * jj + 1], z = buf[3 * jj + 2];
            const float inv = rsqrtf(fmaxf(x * x + y * y + z * z, 1e-30f));
            x *= inv; y *= inv; z *= inv;
            unsigned int* __restrict__ w32 =
                (unsigned int*)&sh[r * LDSW + D_DIM + (h * 10 + jj) * 6];
            w32[0] = pack2(x * x, y * y);
            w32[1] = pack2(z * z, s2 * x * y);
            w32[2] = pack2(s2 * x * z, s2 * y * z);
        }
        // zero pad cols 184..191
        if (h == 1) *(uint4*)&sh[r * LDSW + 184] = (uint4){0u, 0u, 0u, 0u};
    }
    __syncthreads();

    // ---- MFMA phase ----
    const int w  = tid >> 6;   // wave id -> 16-row strip
    const int l  = tid & 63;
    const int lr = l & 15;     // frag row/col
    const int kg = l >> 4;     // k-group (8 consecutive k)

    f32x4 accP[4], accW[4];
    #pragma unroll
    for (int c4 = 0; c4 < 4; ++c4) {
        accP[c4] = (f32x4){0.f, 0.f, 0.f, 0.f};
        accW[c4] = (f32x4){0.f, 0.f, 0.f, 0.f};
    }

    const unsigned short* Abase = &Ash[(w * 16 + lr) * LDSW + kg * 8];
    const unsigned short* Bbase = &Bsh[lr * LDSW + kg * 8];

    #pragma unroll
    for (int ks = 0; ks < 6; ++ks) {
        const bf16x8 af = *(const bf16x8*)(Abase + ks * 32);
        #pragma unroll
        for (int c4 = 0; c4 < 4; ++c4) {
            const bf16x8 bf = *(const bf16x8*)(Bbase + c4 * 16 * LDSW + ks * 32);
            if (ks < 2)
                accP[c4] = __builtin_amdgcn_mfma_f32_16x16x32_bf16(af, bf, accP[c4], 0, 0, 0);
            else
                accW[c4] = __builtin_amdgcn_mfma_f32_16x16x32_bf16(af, bf, accW[c4], 0, 0, 0);
        }
    }

    // ---- epilogue: D[row=(l>>4)*4+reg][col=l&15] ----
    const int ri0 = w * 16 + kg * 4;          // local A row of acc reg 0
    const int i0  = ib * 64 + ri0;
    float sqi[4];
    #pragma unroll
    for (int r = 0; r < 4; ++r) sqi[r] = sqA[ri0 + r];

    float local = 0.0f;
    #pragma unroll
    for (int c4 = 0; c4 < 4; ++c4) {
        const int jl = c4 * 16 + lr;
        const int j  = jb * 64 + jl;
        const float sqj = sqB[jl];
        #pragma unroll
        for (int r = 0; r < 4; ++r) {
            const int i = i0 + r;
            if (j > i) {
                const float d2   = fmaxf(sqi[r] + sqj - 2.0f * accP[c4][r], 0.0f);
                const float dist = sqrtf(d2);
                const float s    = fmaxf((float)N_J - accW[c4][r], 0.0f);
                local += fabsf(dist - sqrtf(s));
            }
        }
    }

    // wave reduce -> block partial (deterministic, no atomics)
    #pragma unroll
    for (int off = 32; off > 0; off >>= 1) local += __shfl_down(local, off);
    if (l == 0) wsum[w] = local;
    __syncthreads();
    if (tid == 0) partials[blockIdx.x] = wsum[0] + wsum[1] + wsum[2] + wsum[3];
}

// ---------------------------------------------------------------------------
// Finalize: deterministic f64 sum of 528 partials, divide by pair count.
// ---------------------------------------------------------------------------
__global__ __launch_bounds__(256)
void finalize_kernel(const float* __restrict__ partials, float* __restrict__ out) {
    __shared__ double sh[256];
    double s = 0.0;
    for (int i = threadIdx.x; i < NTILES; i += 256) s += (double)partials[i];
    sh[threadIdx.x] = s;
    __syncthreads();
    for (int off = 128; off > 0; off >>= 1) {
        if (threadIdx.x < off) sh[threadIdx.x] += sh[threadIdx.x + off];
        __syncthreads();
    }
    if (threadIdx.x == 0) out[0] = (float)(sh[0] / NUM_PAIRS_D);
}

// ---------------------------------------------------------------------------
extern "C" void kernel_launch(void* const* d_in, const int* in_sizes, int n_in,
                              void* d_out, int out_size, void* d_ws, size_t ws_size,
                              hipStream_t stream) {
    const float* pred = (const float*)d_in[0];   // [2048, 64] f32
    const float* data = (const float*)d_in[1];   // [2048, 20, 3] f32
    float* out = (float*)d_out;

    float* partials = (float*)d_ws;              // 528 f32

    pairloss_kernel<<<NTILES, 256, 0, stream>>>(pred, data, partials);
    finalize_kernel<<<1, 256, 0, stream>>>(partials, out);
}

// Round 4
// 18.157 us; speedup vs baseline: 2.5308x; 1.0898x over previous
//
#include <hip/hip_runtime.h>

// Fixed problem shapes
#define N_PTS 2048
#define D_DIM 64
#define N_J   20
#define KD    192    // 64 pred + 2x(60 features + 4 zero pad)
#define LDSW  200    // LDS row stride (bf16): 400 B = 25 16B-slots; 25 is odd ->
                     // row-to-row slot phase advances 1 mod 8: every b128 access
                     // pattern lands exactly 8 lanes per bank-phase (conflict-free)
#define T_TILES 32   // 2048/64
#define NTILES 528   // T*(T+1)/2 upper-triangle 64x64 tiles
#define NUM_PAIRS_D 2098175.0   // N*(N+1)/2 - 1 (reference normalizer)

typedef __attribute__((ext_vector_type(8))) short bf16x8;   // MFMA A/B frag
typedef __attribute__((ext_vector_type(4))) float f32x4;    // MFMA C/D frag

// round-to-nearest-even f32 -> bf16 bits
__device__ inline unsigned short f2bf(float f) {
    union { float f; unsigned int u; } v; v.f = f;
    unsigned int u = v.u;
    return (unsigned short)((u + 0x7FFFu + ((u >> 16) & 1u)) >> 16);
}
__device__ inline unsigned int pack2(float lo, float hi) {
    return (unsigned int)f2bf(lo) | ((unsigned int)f2bf(hi) << 16);
}

// ---------------------------------------------------------------------------
// One block per 64x64 upper-triangle pair tile. Feature columns use a fixed
// k-permutation (dot-invariant): k[0:64) = pred, k[64:128) = joints 0-9
// lifted features (60) + 4 zeros, k[128:192) = joints 10-19 (60) + 4 zeros.
// Each half-row worker owns a contiguous 128 B span -> all-b128 staging.
// 4 waves x 4 MFMA col-tiles, K=192 in 6 steps (2 -> accP, 4 -> accW).
// Epilogue: |dist-dis| per strict-upper pair, wave reduce, one store/block.
// ---------------------------------------------------------------------------
__global__ __launch_bounds__(256, 3)
void pairloss_kernel(const float* __restrict__ pred,
                     const float* __restrict__ data,
                     float* __restrict__ partials) {
    __shared__ unsigned short Ash[64 * LDSW];
    __shared__ unsigned short Bsh[64 * LDSW];
    __shared__ float sqA[64], sqB[64], wsum[4];

    // closed-form triangular tile decode (+safety fixup)
    const int t = blockIdx.x;
    int ib = (int)((65.0f - sqrtf(4225.0f - 8.0f * (float)t)) * 0.5f);
    if (ib > T_TILES - 1) ib = T_TILES - 1;
    if (ib < 0) ib = 0;
    #define TRI_OFF(i) ((i) * T_TILES - ((i) * ((i) - 1)) / 2)
    while (ib > 0 && t < TRI_OFF(ib)) --ib;
    while (ib < T_TILES - 1 && t >= TRI_OFF(ib + 1)) ++ib;
    const int jb = ib + (t - TRI_OFF(ib));

    const int tid = threadIdx.x;

    // ---- staging: threads 0..127 build A (rows of ib), 128..255 build B ----
    {
        const int half = tid >> 7;          // 0 = A, 1 = B
        const int r    = (tid >> 1) & 63;   // row within tile
        const int h    = tid & 1;           // half-row worker
        const int grow = (half ? jb : ib) * 64 + r;
        unsigned short* __restrict__ sh = half ? Bsh : Ash;

        // pred part: 32 f32 -> 4 x b128 bf16 stores (+ exact f32 sq-norm)
        const float4* __restrict__ p4 = (const float4*)&pred[grow * D_DIM + h * 32];
        float s = 0.f;
        #pragma unroll
        for (int q = 0; q < 4; ++q) {
            const float4 v0 = p4[2 * q];
            const float4 v1 = p4[2 * q + 1];
            s += v0.x * v0.x + v0.y * v0.y + v0.z * v0.z + v0.w * v0.w
               + v1.x * v1.x + v1.y * v1.y + v1.z * v1.z + v1.w * v1.w;
            uint4 u;
            u.x = pack2(v0.x, v0.y);
            u.y = pack2(v0.z, v0.w);
            u.z = pack2(v1.x, v1.y);
            u.w = pack2(v1.z, v1.w);
            *(uint4*)&sh[r * LDSW + h * 32 + q * 8] = u;
        }
        s += __shfl_xor(s, 1);
        if (h == 0) (half ? sqB : sqA)[r] = s;

        // joint part: 10 joints -> 30 bf16x2 dwords + 2 zero dwords = 8 x b128
        const float2* __restrict__ d2 = (const float2*)&data[grow * (N_J * 3) + h * 30];
        float buf[30];
        #pragma unroll
        for (int q = 0; q < 15; ++q) {
            const float2 v = d2[q];
            buf[2 * q] = v.x; buf[2 * q + 1] = v.y;
        }
        unsigned int wreg[32];
        const float s2 = 1.4142135623730951f;
        #pragma unroll
        for (int jj = 0; jj < 10; ++jj) {
            float x = buf[3 * jj], y = buf[3 * jj + 1], z = buf[3 * jj + 2];
            const float inv = rsqrtf(fmaxf(x * x + y * y + z * z, 1e-30f));
            x *= inv; y *= inv; z *= inv;
            wreg[3 * jj + 0] = pack2(x * x, y * y);
            wreg[3 * jj + 1] = pack2(z * z, s2 * x * y);
            wreg[3 * jj + 2] = pack2(s2 * x * z, s2 * y * z);
        }
        wreg[30] = 0u; wreg[31] = 0u;
        #pragma unroll
        for (int q = 0; q < 8; ++q) {
            uint4 u;
            u.x = wreg[4 * q + 0]; u.y = wreg[4 * q + 1];
            u.z = wreg[4 * q + 2]; u.w = wreg[4 * q + 3];
            *(uint4*)&sh[r * LDSW + D_DIM + h * 64 + q * 8] = u;
        }
    }
    __syncthreads();

    // ---- MFMA phase ----
    const int w  = tid >> 6;   // wave -> 16-row strip
    const int l  = tid & 63;
    const int lr = l & 15;     // frag row/col
    const int kg = l >> 4;     // k-group

    f32x4 accP[4], accW[4];
    #pragma unroll
    for (int c4 = 0; c4 < 4; ++c4) {
        accP[c4] = (f32x4){0.f, 0.f, 0.f, 0.f};
        accW[c4] = (f32x4){0.f, 0.f, 0.f, 0.f};
    }

    const unsigned short* Abase = &Ash[(w * 16 + lr) * LDSW + kg * 8];
    const unsigned short* Bbase = &Bsh[lr * LDSW + kg * 8];

    __builtin_amdgcn_s_setprio(1);
    #pragma unroll
    for (int ks = 0; ks < 6; ++ks) {
        const bf16x8 af = *(const bf16x8*)(Abase + ks * 32);
        #pragma unroll
        for (int c4 = 0; c4 < 4; ++c4) {
            const bf16x8 bf = *(const bf16x8*)(Bbase + c4 * 16 * LDSW + ks * 32);
            if (ks < 2)
                accP[c4] = __builtin_amdgcn_mfma_f32_16x16x32_bf16(af, bf, accP[c4], 0, 0, 0);
            else
                accW[c4] = __builtin_amdgcn_mfma_f32_16x16x32_bf16(af, bf, accW[c4], 0, 0, 0);
        }
    }
    __builtin_amdgcn_s_setprio(0);

    // ---- epilogue: D[row=(l>>4)*4+reg][col=l&15] ----
    const int ri0 = w * 16 + kg * 4;
    const int i0  = ib * 64 + ri0;
    float sqi[4];
    #pragma unroll
    for (int r = 0; r < 4; ++r) sqi[r] = sqA[ri0 + r];

    float local = 0.0f;
    #pragma unroll
    for (int c4 = 0; c4 < 4; ++c4) {
        const int jl = c4 * 16 + lr;
        const int j  = jb * 64 + jl;
        const float sqj = sqB[jl];
        #pragma unroll
        for (int r = 0; r < 4; ++r) {
            const int i = i0 + r;
            if (j > i) {
                const float d2   = fmaxf(sqi[r] + sqj - 2.0f * accP[c4][r], 0.0f);
                const float dist = sqrtf(d2);
                const float s    = fmaxf((float)N_J - accW[c4][r], 0.0f);
                local += fabsf(dist - sqrtf(s));
            }
        }
    }

    // wave reduce -> block partial (deterministic, no atomics)
    #pragma unroll
    for (int off = 32; off > 0; off >>= 1) local += __shfl_down(local, off);
    if (l == 0) wsum[w] = local;
    __syncthreads();
    if (tid == 0) partials[blockIdx.x] = wsum[0] + wsum[1] + wsum[2] + wsum[3];
}

// ---------------------------------------------------------------------------
// Finalize: deterministic f64 sum of 528 partials (fixed lane->index map).
// ---------------------------------------------------------------------------
__global__ __launch_bounds__(256)
void finalize_kernel(const float* __restrict__ partials, float* __restrict__ out) {
    double s = 0.0;
    for (int i = threadIdx.x; i < NTILES; i += 256) s += (double)partials[i];
    #pragma unroll
    for (int off = 32; off > 0; off >>= 1) s += __shfl_down(s, off);
    __shared__ double sh4[4];
    if ((threadIdx.x & 63) == 0) sh4[threadIdx.x >> 6] = s;
    __syncthreads();
    if (threadIdx.x == 0)
        out[0] = (float)((sh4[0] + sh4[1] + sh4[2] + sh4[3]) / NUM_PAIRS_D);
}

// ---------------------------------------------------------------------------
extern "C" void kernel_launch(void* const* d_in, const int* in_sizes, int n_in,
                              void* d_out, int out_size, void* d_ws, size_t ws_size,
                              hipStream_t stream) {
    const float* pred = (const float*)d_in[0];   // [2048, 64] f32
    const float* data = (const float*)d_in[1];   // [2048, 20, 3] f32
    float* out = (float*)d_out;

    float* partials = (float*)d_ws;              // 528 f32

    pairloss_kernel<<<NTILES, 256, 0, stream>>>(pred, data, partials);
    finalize_kernel<<<1, 256, 0, stream>>>(partials, out);
}

// Round 5
// 17.926 us; speedup vs baseline: 2.5634x; 1.0129x over previous
//
#include <hip/hip_runtime.h>

// Fixed problem shapes
#define N_PTS 2048
#define D_DIM 64
#define N_J   20
#define KD    192    // 64 pred + 2x(60 features + 4 zero pad)
#define LDSW  200    // LDS row stride (bf16): 400 B = 25 16B-slots; 25 is odd ->
                     // row-to-row slot phase advances 1 mod 8: every b128 access
                     // pattern lands exactly 8 lanes per bank-phase (conflict-free)
#define T_TILES 32   // 2048/64
#define NTILES 528   // T*(T+1)/2 upper-triangle 64x64 tiles
#define NUM_PAIRS_D 2098175.0   // N*(N+1)/2 - 1 (reference normalizer)

typedef __attribute__((ext_vector_type(8))) short bf16x8;   // MFMA A/B frag
typedef __attribute__((ext_vector_type(4))) float f32x4;    // MFMA C/D frag

// round-to-nearest-even f32 -> bf16 bits
__device__ inline unsigned short f2bf(float f) {
    union { float f; unsigned int u; } v; v.f = f;
    unsigned int u = v.u;
    return (unsigned short)((u + 0x7FFFu + ((u >> 16) & 1u)) >> 16);
}
__device__ inline unsigned int pack2(float lo, float hi) {
    return (unsigned int)f2bf(lo) | ((unsigned int)f2bf(hi) << 16);
}

// ---------------------------------------------------------------------------
// One block per 64x64 upper-triangle pair tile. Feature columns use a fixed
// k-permutation (dot-invariant): k[0:64) = pred, k[64:128) = joints 0-9
// lifted features (60) + 4 zeros, k[128:192) = joints 10-19 (60) + 4 zeros.
// Each half-row worker owns a contiguous 128 B span -> all-b128 staging.
// 4 waves x 4 MFMA col-tiles, K=192 in 6 steps (2 -> accP, 4 -> accW).
// Epilogue: |dist-dis| per strict-upper pair, wave reduce, one store/block.
// ---------------------------------------------------------------------------
__global__ __launch_bounds__(256, 3)
void pairloss_kernel(const float* __restrict__ pred,
                     const float* __restrict__ data,
                     float* __restrict__ partials) {
    __shared__ unsigned short Ash[64 * LDSW];
    __shared__ unsigned short Bsh[64 * LDSW];
    __shared__ float sqA[64], sqB[64], wsum[4];

    // closed-form triangular tile decode (+safety fixup)
    const int t = blockIdx.x;
    int ib = (int)((65.0f - sqrtf(4225.0f - 8.0f * (float)t)) * 0.5f);
    if (ib > T_TILES - 1) ib = T_TILES - 1;
    if (ib < 0) ib = 0;
    #define TRI_OFF(i) ((i) * T_TILES - ((i) * ((i) - 1)) / 2)
    while (ib > 0 && t < TRI_OFF(ib)) --ib;
    while (ib < T_TILES - 1 && t >= TRI_OFF(ib + 1)) ++ib;
    const int jb = ib + (t - TRI_OFF(ib));

    const int tid = threadIdx.x;

    // ---- staging: threads 0..127 build A (rows of ib), 128..255 build B ----
    {
        const int half = tid >> 7;          // 0 = A, 1 = B
        const int r    = (tid >> 1) & 63;   // row within tile
        const int h    = tid & 1;           // half-row worker
        const int grow = (half ? jb : ib) * 64 + r;
        unsigned short* __restrict__ sh = half ? Bsh : Ash;

        // pred part: 32 f32 -> 4 x b128 bf16 stores (+ exact f32 sq-norm)
        const float4* __restrict__ p4 = (const float4*)&pred[grow * D_DIM + h * 32];
        float s = 0.f;
        #pragma unroll
        for (int q = 0; q < 4; ++q) {
            const float4 v0 = p4[2 * q];
            const float4 v1 = p4[2 * q + 1];
            s += v0.x * v0.x + v0.y * v0.y + v0.z * v0.z + v0.w * v0.w
               + v1.x * v1.x + v1.y * v1.y + v1.z * v1.z + v1.w * v1.w;
            uint4 u;
            u.x = pack2(v0.x, v0.y);
            u.y = pack2(v0.z, v0.w);
            u.z = pack2(v1.x, v1.y);
            u.w = pack2(v1.z, v1.w);
            *(uint4*)&sh[r * LDSW + h * 32 + q * 8] = u;
        }
        s += __shfl_xor(s, 1);
        if (h == 0) (half ? sqB : sqA)[r] = s;

        // joint part: 10 joints -> 30 bf16x2 dwords + 2 zero dwords = 8 x b128
        const float2* __restrict__ d2 = (const float2*)&data[grow * (N_J * 3) + h * 30];
        float buf[30];
        #pragma unroll
        for (int q = 0; q < 15; ++q) {
            const float2 v = d2[q];
            buf[2 * q] = v.x; buf[2 * q + 1] = v.y;
        }
        unsigned int wreg[32];
        const float s2 = 1.4142135623730951f;
        #pragma unroll
        for (int jj = 0; jj < 10; ++jj) {
            float x = buf[3 * jj], y = buf[3 * jj + 1], z = buf[3 * jj + 2];
            const float inv = rsqrtf(fmaxf(x * x + y * y + z * z, 1e-30f));
            x *= inv; y *= inv; z *= inv;
            wreg[3 * jj + 0] = pack2(x * x, y * y);
            wreg[3 * jj + 1] = pack2(z * z, s2 * x * y);
            wreg[3 * jj + 2] = pack2(s2 * x * z, s2 * y * z);
        }
        wreg[30] = 0u; wreg[31] = 0u;
        #pragma unroll
        for (int q = 0; q < 8; ++q) {
            uint4 u;
            u.x = wreg[4 * q + 0]; u.y = wreg[4 * q + 1];
            u.z = wreg[4 * q + 2]; u.w = wreg[4 * q + 3];
            *(uint4*)&sh[r * LDSW + D_DIM + h * 64 + q * 8] = u;
        }
    }
    __syncthreads();

    // ---- MFMA phase ----
    const int w  = tid >> 6;   // wave -> 16-row strip
    const int l  = tid & 63;
    const int lr = l & 15;     // frag row/col
    const int kg = l >> 4;     // k-group

    f32x4 accP[4], accW[4];
    #pragma unroll
    for (int c4 = 0; c4 < 4; ++c4) {
        accP[c4] = (f32x4){0.f, 0.f, 0.f, 0.f};
        accW[c4] = (f32x4){0.f, 0.f, 0.f, 0.f};
    }

    const unsigned short* Abase = &Ash[(w * 16 + lr) * LDSW + kg * 8];
    const unsigned short* Bbase = &Bsh[lr * LDSW + kg * 8];

    __builtin_amdgcn_s_setprio(1);
    #pragma unroll
    for (int ks = 0; ks < 6; ++ks) {
        const bf16x8 af = *(const bf16x8*)(Abase + ks * 32);
        #pragma unroll
        for (int c4 = 0; c4 < 4; ++c4) {
            const bf16x8 bf = *(const bf16x8*)(Bbase + c4 * 16 * LDSW + ks * 32);
            if (ks < 2)
                accP[c4] = __builtin_amdgcn_mfma_f32_16x16x32_bf16(af, bf, accP[c4], 0, 0, 0);
            else
                accW[c4] = __builtin_amdgcn_mfma_f32_16x16x32_bf16(af, bf, accW[c4], 0, 0, 0);
        }
    }
    __builtin_amdgcn_s_setprio(0);

    // ---- epilogue: D[row=(l>>4)*4+reg][col=l&15] ----
    const int ri0 = w * 16 + kg * 4;
    const int i0  = ib * 64 + ri0;
    float sqi[4];
    #pragma unroll
    for (int r = 0; r < 4; ++r) sqi[r] = sqA[ri0 + r];

    float local = 0.0f;
    #pragma unroll
    for (int c4 = 0; c4 < 4; ++c4) {
        const int jl = c4 * 16 + lr;
        const int j  = jb * 64 + jl;
        const float sqj = sqB[jl];
        #pragma unroll
        for (int r = 0; r < 4; ++r) {
            const int i = i0 + r;
            if (j > i) {
                const float d2   = fmaxf(sqi[r] + sqj - 2.0f * accP[c4][r], 0.0f);
                const float dist = sqrtf(d2);
                const float s    = fmaxf((float)N_J - accW[c4][r], 0.0f);
                local += fabsf(dist - sqrtf(s));
            }
        }
    }

    // wave reduce -> block partial (deterministic, no atomics)
    #pragma unroll
    for (int off = 32; off > 0; off >>= 1) local += __shfl_down(local, off);
    if (l == 0) wsum[w] = local;
    __syncthreads();
    if (tid == 0) partials[blockIdx.x] = wsum[0] + wsum[1] + wsum[2] + wsum[3];
}

// ---------------------------------------------------------------------------
// Finalize: deterministic f64 sum of 528 partials (fixed lane->index map).
// ---------------------------------------------------------------------------
__global__ __launch_bounds__(256)
void finalize_kernel(const float* __restrict__ partials, float* __restrict__ out) {
    double s = 0.0;
    for (int i = threadIdx.x; i < NTILES; i += 256) s += (double)partials[i];
    #pragma unroll
    for (int off = 32; off > 0; off >>= 1) s += __shfl_down(s, off);
    __shared__ double sh4[4];
    if ((threadIdx.x & 63) == 0) sh4[threadIdx.x >> 6] = s;
    __syncthreads();
    if (threadIdx.x == 0)
        out[0] = (float)((sh4[0] + sh4[1] + sh4[2] + sh4[3]) / NUM_PAIRS_D);
}

// ---------------------------------------------------------------------------
extern "C" void kernel_launch(void* const* d_in, const int* in_sizes, int n_in,
                              void* d_out, int out_size, void* d_ws, size_t ws_size,
                              hipStream_t stream) {
    const float* pred = (const float*)d_in[0];   // [2048, 64] f32
    const float* data = (const float*)d_in[1];   // [2048, 20, 3] f32
    float* out = (float*)d_out;

    float* partials = (float*)d_ws;              // 528 f32

    pairloss_kernel<<<NTILES, 256, 0, stream>>>(pred, data, partials);
    finalize_kernel<<<1, 256, 0, stream>>>(partials, out);
}